// Round 2
// baseline (5530.162 us; speedup 1.0000x reference)
//
#include <hip/hip_runtime.h>
#include <hip/hip_fp16.h>

#define T_SZ 365
#define IN_SZ 32
#define H_SZ 256
#define G4 1024
#define K_SZ 288
#define M_SLAB 16         // rows per slab
#define SLABS 2           // independent slabs per group (latency hiding)
#define M_BLK 32          // rows per group = SLABS * M_SLAB
#define NGRP 128          // groups: 128 * 32 = 4096 rows
#define NTHR 512          // 8 waves, each owns a distinct 16-col W slice
#define NBLK 256          // 1 block per CU
#define XPB 80            // x_s row stride bytes (40 halfs, padded)
#define HROWB 512         // bytes per hs row (256 halfs, dense + XOR swizzle)
#define HS_SLAB (M_SLAB * HROWB)   // 8192 B per slab image

// workspace offsets (bytes)
#define ARR_OFF (640*1024)
#define HX_OFF  (1024*1024)

typedef _Float16 f16x8 __attribute__((ext_vector_type(8)));
typedef _Float16 f16x2 __attribute__((ext_vector_type(2)));
typedef float f32x4 __attribute__((ext_vector_type(4)));
typedef unsigned long long u64;

__device__ __forceinline__ float fast_sigmoid(float x) {
    float e = __builtin_amdgcn_exp2f(-1.4426950408889634f * x);
    return __builtin_amdgcn_rcpf(1.0f + e);
}
__device__ __forceinline__ float fast_tanh(float x) {
    float e = __builtin_amdgcn_exp2f(2.8853900817779268f * x);
    return 1.0f - 2.0f * __builtin_amdgcn_rcpf(1.0f + e);
}

// Pack W = [w_hh | w_ih] as fp16, layout [gate-row][k] (k contiguous) = B^T.
__global__ void pack_w_kernel(const float* __restrict__ w_ih,
                              const float* __restrict__ w_hh,
                              _Float16* __restrict__ wp) {
    int idx = blockIdx.x * 256 + threadIdx.x;
    if (idx >= G4 * K_SZ) return;
    int g = idx / K_SZ, k = idx - g * K_SZ;
    float v = (k < H_SZ) ? w_hh[g * H_SZ + k] : w_ih[g * IN_SZ + (k - H_SZ)];
    wp[idx] = (_Float16)v;
}

__global__ void init_sync_kernel(unsigned int* arrive) {
    for (int i = threadIdx.x; i < NGRP * 4 * 16; i += 256) arrive[i] = 0u;
}

__global__ __launch_bounds__(NTHR, 2) void lstm_kernel(
    const float* __restrict__ xd, const float* __restrict__ b,
    const _Float16* __restrict__ wp, const float* __restrict__ w_out,
    const float* __restrict__ b_out, float* __restrict__ out,
    u64* hx, unsigned int* arrive)
{
    // h: [buffer 0/1][slab 0/1][16 rows][512 B], rows XOR-swizzled (bits 4..6)
    __shared__ __align__(16) char hsb[2 * SLABS * HS_SLAB];   // 32 KB
    __shared__ __align__(16) char x_s[SLABS * M_SLAB * XPB];  // 2.5 KB

    const int tid  = threadIdx.x;
    const int wq   = tid >> 6;        // wave 0..7
    const int lane = tid & 63;
    const int quad = lane >> 4;
    const int l16  = lane & 15;
    const int blk  = blockIdx.x;
    const int g    = blk & (NGRP - 1);
    const int q    = blk >> 7;           // pair member 0/1 (blk, blk+128: same XCD)

    const int jcol = q * 128 + wq * 16 + l16;   // this lane's global h column

    // ---- W slice (4 gates x 16 j-cols x K=288) in registers/AGPRs ----
    f16x8 wfr[4][9];
#pragma unroll
    for (int G = 0; G < 4; ++G) {
        const _Float16* wr = wp + (size_t)(G * 256 + jcol) * K_SZ + quad * 8;
#pragma unroll
        for (int kt = 0; kt < 9; ++kt)
            wfr[G][kt] = *(const f16x8*)(wr + kt * 32);
    }
    float bias[4];
#pragma unroll
    for (int G = 0; G < 4; ++G) bias[G] = b[G * 256 + jcol];

    // ---- loop-invariant swizzled A-read offsets (16 rows per slab) ----
    const int swz_l = (l16 & 7) << 4;
    int a_off[8];
#pragma unroll
    for (int kt = 0; kt < 8; ++kt)
        a_off[kt] = l16 * HROWB + ((kt * 64 + quad * 16) ^ swz_l);
    const int x_off = l16 * XPB + quad * 16;

    // x loader: 32 group rows, 16 threads/row, 2 floats each
    const int xr = tid >> 4;            // 0..31 group row
    const int xe = tid & 15;
    const int xs_byte = (xr >> 4) * (M_SLAB * XPB) + (xr & 15) * XPB + xe * 4;
    const float* xrow = xd + (size_t)(g * M_BLK + xr) * (T_SZ * IN_SZ) + xe * 2;
    float2 xa = *(const float2*)xrow;

    // push/pull addressing: m = tid>>5 (16 rows), w = tid&31 (u64 unit in half-row)
    const int pm = tid >> 5, pw = tid & 31;
    const int swz_m = (pm & 7) << 4;
    const int push_b  = pm * HROWB + ((q * 256 + pw * 8) ^ swz_m);        // LDS byte
    const int pull_b  = pm * HROWB + (((1 - q) * 256 + pw * 8) ^ swz_m);  // LDS byte
    const int push_u  = pm * 64 + q * 32 + pw;          // hx u64 idx (lane-dense)
    const int pull_u  = pm * 64 + (1 - q) * 32 + pw;

    // zero both slabs of buffer 0 (h_0 = 0): 64 B per thread
    {
        u64* z = (u64*)hsb;
#pragma unroll
        for (int i = 0; i < 4; ++i) z[tid * 4 + i] = 0ull;
    }
    // stage x_0
    *(f16x2*)(x_s + xs_byte) = (f16x2){(_Float16)xa.x, (_Float16)xa.y};

    f32x4 creg[SLABS];
    creg[0] = (f32x4){0.f, 0.f, 0.f, 0.f};
    creg[1] = (f32x4){0.f, 0.f, 0.f, 0.f};

    __syncthreads();

    unsigned int* fmy[SLABS];
    unsigned int* fpr[SLABS];
#pragma unroll
    for (int s = 0; s < SLABS; ++s) {
        fmy[s] = &arrive[(g * 4 + s * 2 + q) * 16];
        fpr[s] = &arrive[(g * 4 + s * 2 + (1 - q)) * 16];
    }
    const f32x4 vzero = {0.f, 0.f, 0.f, 0.f};

    int pb = 0;
    for (int t = 0; t < T_SZ; ++t) {
        // ---------- per-slab: GEMM -> act -> push -> flag ----------
#pragma unroll
        for (int s = 0; s < SLABS; ++s) {
            const char* hsR = hsb + (pb * SLABS + s) * HS_SLAB;       // h_t
            char* hsW = hsb + ((pb ^ 1) * SLABS + s) * HS_SLAB;       // h_{t+1}

            f32x4 acc[4];
#pragma unroll
            for (int G = 0; G < 4; ++G) acc[G] = vzero;

#pragma unroll
            for (int kt = 0; kt < 8; ++kt) {
                f16x8 a0 = *(const f16x8*)(hsR + a_off[kt]);
#pragma unroll
                for (int G = 0; G < 4; ++G)
                    acc[G] = __builtin_amdgcn_mfma_f32_16x16x32_f16(a0, wfr[G][kt], acc[G], 0, 0, 0);
            }
            {   // x part (k 256..287)
                f16x8 a0 = *(const f16x8*)(x_s + s * (M_SLAB * XPB) + x_off);
#pragma unroll
                for (int G = 0; G < 4; ++G)
                    acc[G] = __builtin_amdgcn_mfma_f32_16x16x32_f16(a0, wfr[G][8], acc[G], 0, 0, 0);
            }

            // activations + state update; own cols -> hsW (swizzled)
#pragma unroll
            for (int r = 0; r < 4; ++r) {
                float iv = fast_sigmoid(acc[0][r] + bias[0]);
                float fv = fast_sigmoid(acc[1][r] + bias[1]);
                float gv = fast_tanh  (acc[2][r] + bias[2]);
                float ov = fast_sigmoid(acc[3][r] + bias[3]);
                float cv = fv * creg[s][r] + iv * gv;
                creg[s][r] = cv;
                float hv = ov * fast_tanh(cv);
                int m = quad * 4 + r;
                *(_Float16*)(hsW + m * HROWB + ((jcol * 2) ^ ((m & 7) << 4))) = (_Float16)hv;
            }
            __syncthreads();   // own half of slab s complete in hsW

            // push own half (4 KB): one lane-dense u64 per thread (full-line coverage)
            u64* hxg = hx + ((size_t)(pb * SLABS + s) * NGRP + g) * (HS_SLAB / 8);
            __hip_atomic_store(&hxg[push_u], *(const u64*)(hsW + push_b),
                               __ATOMIC_RELAXED, __HIP_MEMORY_SCOPE_AGENT);
            asm volatile("s_waitcnt vmcnt(0)" ::: "memory");
            __syncthreads();   // all waves' pushes drained
            if (tid == 0)
                __hip_atomic_store(fmy[s], (unsigned int)(t + 1),
                                   __ATOMIC_RELEASE, __HIP_MEMORY_SCOPE_AGENT);
        }

        // prefetch next x (issued now; consumed after the sync window)
        if (t + 1 < T_SZ)
            xa = *(const float2*)(xrow + (size_t)(t + 1) * IN_SZ);

        // ---------- wait partner (both slabs), then pull both ----------
        if (tid == 0) {
            while (__hip_atomic_load(fpr[0], __ATOMIC_ACQUIRE, __HIP_MEMORY_SCOPE_AGENT) < (unsigned int)(t + 1))
                __builtin_amdgcn_s_sleep(2);
            while (__hip_atomic_load(fpr[1], __ATOMIC_ACQUIRE, __HIP_MEMORY_SCOPE_AGENT) < (unsigned int)(t + 1))
                __builtin_amdgcn_s_sleep(2);
        }
        __syncthreads();

        {
            u64* hxA = hx + ((size_t)(pb * SLABS + 0) * NGRP + g) * (HS_SLAB / 8);
            u64* hxB = hx + ((size_t)(pb * SLABS + 1) * NGRP + g) * (HS_SLAB / 8);
            u64 va = __hip_atomic_load(&hxA[pull_u], __ATOMIC_RELAXED, __HIP_MEMORY_SCOPE_AGENT);
            u64 vb = __hip_atomic_load(&hxB[pull_u], __ATOMIC_RELAXED, __HIP_MEMORY_SCOPE_AGENT);
            char* hsWA = hsb + ((pb ^ 1) * SLABS + 0) * HS_SLAB;
            char* hsWB = hsb + ((pb ^ 1) * SLABS + 1) * HS_SLAB;
            *(u64*)(hsWA + pull_b) = va;
            *(u64*)(hsWB + pull_b) = vb;
        }
        // stage x_{t+1}
        if (t + 1 < T_SZ)
            *(f16x2*)(x_s + xs_byte) = (f16x2){(_Float16)xa.x, (_Float16)xa.y};

        __syncthreads();   // full h_{t+1} + x_{t+1} visible
        pb ^= 1;
    }

    // ---- epilogue: out[m] = relu(h_T . w_out + b_out); member q==0 writes ----
    if (q == 0) {
        const int m = tid >> 4, p = tid & 15;        // m: 0..31 group row
        const int s = m >> 4, mr = m & 15;
        const char* hsF = hsb + (pb * SLABS + s) * HS_SLAB + mr * HROWB;
        const int swzm = (mr & 7) << 4;
        float sum = 0.f;
#pragma unroll
        for (int jj = 0; jj < 16; ++jj) {
            int j = p * 16 + jj;
            sum += (float)*(const _Float16*)(hsF + ((j * 2) ^ swzm)) * w_out[j];
        }
        sum += __shfl_xor(sum, 1);
        sum += __shfl_xor(sum, 2);
        sum += __shfl_xor(sum, 4);
        sum += __shfl_xor(sum, 8);
        if (p == 0) out[(size_t)g * M_BLK + m] = fmaxf(sum + b_out[0], 0.f);
    }
}

extern "C" void kernel_launch(void* const* d_in, const int* in_sizes, int n_in,
                              void* d_out, int out_size, void* d_ws, size_t ws_size,
                              hipStream_t stream) {
    const float* xd    = (const float*)d_in[0];
    const float* w_ih  = (const float*)d_in[1];
    const float* w_hh  = (const float*)d_in[2];
    const float* b     = (const float*)d_in[3];
    const float* w_out = (const float*)d_in[4];
    const float* b_out = (const float*)d_in[5];
    float* out = (float*)d_out;

    _Float16* wp = (_Float16*)d_ws;                                 // 576 KB @ 0
    unsigned int* arrive = (unsigned int*)((char*)d_ws + ARR_OFF);  // 32 KB
    u64* hx = (u64*)((char*)d_ws + HX_OFF);                         // 4 MB

    pack_w_kernel<<<(G4 * K_SZ + 255) / 256, 256, 0, stream>>>(w_ih, w_hh, wp);
    init_sync_kernel<<<1, 256, 0, stream>>>(arrive);
    lstm_kernel<<<NBLK, NTHR, 0, stream>>>(xd, b, wp, w_out, b_out, out, hx, arrive);
}

// Round 3
// 1607.767 us; speedup vs baseline: 3.4397x; 3.4397x over previous
//
#include <hip/hip_runtime.h>
#include <hip/hip_fp16.h>

#define T_SZ 365
#define IN_SZ 32
#define H_SZ 256
#define G4 1024
#define K_SZ 288
#define M_BLK 32          // batch rows per group (pair of blocks)
#define NGRP 128          // groups: 128 * 32 = 4096 rows
#define NTHR 512          // 8 waves, each owns a distinct 16-col W slice
#define NBLK 256          // 1 block per CU
#define XPB 80            // x_s row stride bytes (40 halfs, padded)
#define HROWB 512         // bytes per hs row (256 halfs, dense + XOR swizzle)
#define HS_BYTES (M_BLK * HROWB)   // 16 KB per h image

// workspace offsets (bytes)
#define ARR_OFF (640*1024)
#define HX_OFF  (1024*1024)

typedef _Float16 f16x8 __attribute__((ext_vector_type(8)));
typedef _Float16 f16x2 __attribute__((ext_vector_type(2)));
typedef float f32x4 __attribute__((ext_vector_type(4)));
typedef unsigned long long u64;

__device__ __forceinline__ float fast_sigmoid(float x) {
    float e = __builtin_amdgcn_exp2f(-1.4426950408889634f * x);
    return __builtin_amdgcn_rcpf(1.0f + e);
}
__device__ __forceinline__ float fast_tanh(float x) {
    float e = __builtin_amdgcn_exp2f(2.8853900817779268f * x);
    return 1.0f - 2.0f * __builtin_amdgcn_rcpf(1.0f + e);
}

// Pack W = [w_hh | w_ih] as fp16, layout [gate-row][k] (k contiguous) = B^T.
__global__ void pack_w_kernel(const float* __restrict__ w_ih,
                              const float* __restrict__ w_hh,
                              _Float16* __restrict__ wp) {
    int idx = blockIdx.x * 256 + threadIdx.x;
    if (idx >= G4 * K_SZ) return;
    int g = idx / K_SZ, k = idx - g * K_SZ;
    float v = (k < H_SZ) ? w_hh[g * H_SZ + k] : w_ih[g * IN_SZ + (k - H_SZ)];
    wp[idx] = (_Float16)v;
}

__global__ void init_sync_kernel(unsigned int* arrive) {
    for (int i = threadIdx.x; i < NGRP * 2 * 16; i += 256) arrive[i] = 0u;
}

__global__ __launch_bounds__(NTHR, 2) void lstm_kernel(
    const float* __restrict__ xd, const float* __restrict__ b,
    const _Float16* __restrict__ wp, const float* __restrict__ w_out,
    const float* __restrict__ b_out, float* __restrict__ out,
    u64* hx, unsigned int* arrive)
{
    // h double-buffer: dense 512-B rows, XOR-swizzled (byte ^= (row&7)<<4)
    __shared__ __align__(16) char hsb[2 * HS_BYTES];        // 32 KB
    __shared__ __align__(16) char x_s[M_BLK * XPB];         // 2.5 KB

    const int tid  = threadIdx.x;
    const int wq   = tid >> 6;        // wave 0..7
    const int lane = tid & 63;
    const int quad = lane >> 4;
    const int l16  = lane & 15;
    const int blk  = blockIdx.x;
    const int g    = blk & (NGRP - 1);
    const int q    = blk >> 7;           // pair member 0/1 (blk, blk+128: same XCD)

    const int jcol = q * 128 + wq * 16 + l16;   // this lane's global h column

    // ---- W slice (4 gates x 16 j-cols x K=288) in registers: 144 VGPR ----
    f16x8 wfr[4][9];
#pragma unroll
    for (int G = 0; G < 4; ++G) {
        const _Float16* wr = wp + (size_t)(G * 256 + jcol) * K_SZ + quad * 8;
#pragma unroll
        for (int kt = 0; kt < 9; ++kt)
            wfr[G][kt] = *(const f16x8*)(wr + kt * 32);
    }
    float bias[4];
#pragma unroll
    for (int G = 0; G < 4; ++G) bias[G] = b[G * 256 + jcol];

    // ---- loop-invariant swizzled A-read offsets ----
    const int swz_l = (l16 & 7) << 4;
    int a_off[8];
#pragma unroll
    for (int kt = 0; kt < 8; ++kt)
        a_off[kt] = l16 * HROWB + ((kt * 64 + quad * 16) ^ swz_l);
    const int x_off = l16 * XPB + quad * 16;

    // x loader: 32 rows, 16 threads/row, 2 floats each
    const int xr = tid >> 4;
    const int xe = tid & 15;
    const int xs_byte = xr * XPB + xe * 4;
    const float* xrow = xd + (size_t)(g * M_BLK + xr) * (T_SZ * IN_SZ) + xe * 2;
    float2 xa = *(const float2*)xrow;

    // ---- flat-dense push/pull addressing ----
    // own-half flat u64 index u in [0,1024): row = u>>5, w = u&31
    // hx group image: [member 0: 1024 u64][member 1: 1024 u64] (8 KB each, dense)
    const int pr  = tid >> 5;             // rows 0..15 (i=0), +16 (i=1)
    const int pw  = tid & 31;
    const int swz_p = (pr & 7) << 4;      // (pr+16)&7 == pr&7: same swizzle
    const int push_l0 = pr * HROWB + ((q * 256 + pw * 8) ^ swz_p);
    const int pull_l0 = pr * HROWB + (((1 - q) * 256 + pw * 8) ^ swz_p);
    const int push_u0 = q * 1024 + tid;
    const int pull_u0 = (1 - q) * 1024 + tid;

    // zero hs buffer 0 (h_0 = 0): 32 B per thread
    {
        u64* z = (u64*)hsb;
#pragma unroll
        for (int i = 0; i < 4; ++i) z[tid * 4 + i] = 0ull;
    }
    *(f16x2*)(x_s + xs_byte) = (f16x2){(_Float16)xa.x, (_Float16)xa.y};

    f32x4 creg[2];
    creg[0] = (f32x4){0.f, 0.f, 0.f, 0.f};
    creg[1] = (f32x4){0.f, 0.f, 0.f, 0.f};

    __syncthreads();

    unsigned int* myf = &arrive[(g * 2 + q) * 16];
    unsigned int* prf = &arrive[(g * 2 + (1 - q)) * 16];
    const f32x4 vzero = {0.f, 0.f, 0.f, 0.f};

    int pb = 0;
    for (int t = 0; t < T_SZ; ++t) {
        const char* hsR = hsb + pb * HS_BYTES;
        char* hsW = hsb + (pb ^ 1) * HS_BYTES;

        // ---- GEMM: preacts[32 x 128-slice] ----
        f32x4 acc[2][4];
#pragma unroll
        for (int mt = 0; mt < 2; ++mt)
#pragma unroll
            for (int G = 0; G < 4; ++G) acc[mt][G] = vzero;

#pragma unroll
        for (int kt = 0; kt < 8; ++kt) {
            f16x8 a0 = *(const f16x8*)(hsR + a_off[kt]);
            f16x8 a1 = *(const f16x8*)(hsR + a_off[kt] + 16 * HROWB);
#pragma unroll
            for (int G = 0; G < 4; ++G) {
                acc[0][G] = __builtin_amdgcn_mfma_f32_16x16x32_f16(a0, wfr[G][kt], acc[0][G], 0, 0, 0);
                acc[1][G] = __builtin_amdgcn_mfma_f32_16x16x32_f16(a1, wfr[G][kt], acc[1][G], 0, 0, 0);
            }
        }
        {   // x part (k 256..287)
            f16x8 a0 = *(const f16x8*)(x_s + x_off);
            f16x8 a1 = *(const f16x8*)(x_s + x_off + 16 * XPB);
#pragma unroll
            for (int G = 0; G < 4; ++G) {
                acc[0][G] = __builtin_amdgcn_mfma_f32_16x16x32_f16(a0, wfr[G][8], acc[0][G], 0, 0, 0);
                acc[1][G] = __builtin_amdgcn_mfma_f32_16x16x32_f16(a1, wfr[G][8], acc[1][G], 0, 0, 0);
            }
        }

        // ---- activations + state update; own cols -> hsW (swizzled) ----
#pragma unroll
        for (int mt = 0; mt < 2; ++mt) {
#pragma unroll
            for (int r = 0; r < 4; ++r) {
                float iv = fast_sigmoid(acc[mt][0][r] + bias[0]);
                float fv = fast_sigmoid(acc[mt][1][r] + bias[1]);
                float gv = fast_tanh  (acc[mt][2][r] + bias[2]);
                float ov = fast_sigmoid(acc[mt][3][r] + bias[3]);
                float cv = fv * creg[mt][r] + iv * gv;
                creg[mt][r] = cv;
                float hv = ov * fast_tanh(cv);
                int m = mt * 16 + quad * 4 + r;
                *(_Float16*)(hsW + m * HROWB + ((jcol * 2) ^ ((m & 7) << 4))) = (_Float16)hv;
            }
        }
        asm volatile("s_waitcnt lgkmcnt(0)" ::: "memory");
        __builtin_amdgcn_s_barrier();                 // S1: h halves complete in LDS

        // ---- push own half (8 KB, flat-dense), then x prefetch stays in flight ----
        u64* hxg = hx + ((size_t)pb * NGRP + g) * 2048;
        {
            u64 p0 = *(const u64*)(hsW + push_l0);
            u64 p1 = *(const u64*)(hsW + push_l0 + 16 * HROWB);
            __hip_atomic_store(&hxg[push_u0],       p0, __ATOMIC_RELAXED, __HIP_MEMORY_SCOPE_AGENT);
            __hip_atomic_store(&hxg[push_u0 + 512], p1, __ATOMIC_RELAXED, __HIP_MEMORY_SCOPE_AGENT);
        }
        if (t + 1 < T_SZ) {
            xa = *(const float2*)(xrow + (size_t)(t + 1) * IN_SZ);
            asm volatile("s_waitcnt vmcnt(1)" ::: "memory");   // drain 2 pushes, keep x in flight
        } else {
            asm volatile("s_waitcnt vmcnt(0)" ::: "memory");
        }
        __builtin_amdgcn_s_barrier();                 // S2: all waves' pushes at LLC

        // ---- 2-party barrier: RELAXED flag store + RELAXED poll (no cache maint) ----
        if (tid == 0) {
            __hip_atomic_store(myf, (unsigned int)(t + 1),
                               __ATOMIC_RELAXED, __HIP_MEMORY_SCOPE_AGENT);
            while (__hip_atomic_load(prf, __ATOMIC_RELAXED, __HIP_MEMORY_SCOPE_AGENT) < (unsigned int)(t + 1))
                __builtin_amdgcn_s_sleep(1);
        }
        __builtin_amdgcn_s_barrier();                 // S3
        asm volatile("" ::: "memory");

        // ---- pull partner half (8 KB) + stage x_{t+1} ----
        {
            u64 v0 = __hip_atomic_load(&hxg[pull_u0],       __ATOMIC_RELAXED, __HIP_MEMORY_SCOPE_AGENT);
            u64 v1 = __hip_atomic_load(&hxg[pull_u0 + 512], __ATOMIC_RELAXED, __HIP_MEMORY_SCOPE_AGENT);
            *(u64*)(hsW + pull_l0)              = v0;
            *(u64*)(hsW + pull_l0 + 16 * HROWB) = v1;
        }
        if (t + 1 < T_SZ)
            *(f16x2*)(x_s + xs_byte) = (f16x2){(_Float16)xa.x, (_Float16)xa.y};
        asm volatile("s_waitcnt lgkmcnt(0)" ::: "memory");
        __builtin_amdgcn_s_barrier();                 // S4: full h_{t+1} + x_{t+1} visible
        pb ^= 1;
    }

    // ---- epilogue: out[m] = relu(h_T . w_out + b_out); member q==0 writes ----
    if (q == 0) {
        const char* hsF = hsb + pb * HS_BYTES;
        const int m = tid >> 4, p = tid & 15;
        const int swzm = (m & 7) << 4;
        float sum = 0.f;
#pragma unroll
        for (int jj = 0; jj < 16; ++jj) {
            int j = p * 16 + jj;
            sum += (float)*(const _Float16*)(hsF + m * HROWB + ((j * 2) ^ swzm)) * w_out[j];
        }
        sum += __shfl_xor(sum, 1);
        sum += __shfl_xor(sum, 2);
        sum += __shfl_xor(sum, 4);
        sum += __shfl_xor(sum, 8);
        if (p == 0) out[(size_t)g * M_BLK + m] = fmaxf(sum + b_out[0], 0.f);
    }
}

extern "C" void kernel_launch(void* const* d_in, const int* in_sizes, int n_in,
                              void* d_out, int out_size, void* d_ws, size_t ws_size,
                              hipStream_t stream) {
    const float* xd    = (const float*)d_in[0];
    const float* w_ih  = (const float*)d_in[1];
    const float* w_hh  = (const float*)d_in[2];
    const float* b     = (const float*)d_in[3];
    const float* w_out = (const float*)d_in[4];
    const float* b_out = (const float*)d_in[5];
    float* out = (float*)d_out;

    _Float16* wp = (_Float16*)d_ws;                                 // 576 KB @ 0
    unsigned int* arrive = (unsigned int*)((char*)d_ws + ARR_OFF);  // 16 KB
    u64* hx = (u64*)((char*)d_ws + HX_OFF);                         // 4 MB

    pack_w_kernel<<<(G4 * K_SZ + 255) / 256, 256, 0, stream>>>(w_ih, w_hh, wp);
    init_sync_kernel<<<1, 256, 0, stream>>>(arrive);
    lstm_kernel<<<NBLK, NTHR, 0, stream>>>(xd, b, wp, w_out, b_out, out, hx, arrive);
}